// Round 14
// baseline (254.041 us; speedup 1.0000x reference)
//
#include <hip/hip_runtime.h>

#define S_  512
#define F_  64
#define H_  32
#define GQ  128   // 4*H
#define BT  4     // real batch rows per block
#define NB  512   // 2048/BT -> two blocks per CU

#define XS  72    // x plane row stride (ushorts)
#define HS  40    // h plane row stride (ushorts)
#define GS  33    // head buffer row stride (floats)

typedef __attribute__((ext_vector_type(8))) short bf16x8;
typedef __attribute__((ext_vector_type(4))) float f32x4;

// f32 -> (bf16_hi << 16) | bf16_lo, both RNE
__device__ __forceinline__ unsigned pack_split(float f) {
    unsigned u  = __builtin_bit_cast(unsigned, f);
    unsigned hi = (u + 0x7FFFu + ((u >> 16) & 1u)) & 0xFFFF0000u;
    float    fl = f - __builtin_bit_cast(float, hi);
    unsigned ul = __builtin_bit_cast(unsigned, fl);
    unsigned lo = (ul + 0x7FFFu + ((ul >> 16) & 1u)) >> 16;
    return hi | lo;
}

// f32 -> bf16 (RNE)
__device__ __forceinline__ unsigned short bf16_rne(float f) {
    unsigned u = __builtin_bit_cast(unsigned, f);
    return (unsigned short)((u + 0x7FFFu + ((u >> 16) & 1u)) >> 16);
}

__device__ __forceinline__ float sigm(float z) {
    return __builtin_amdgcn_rcpf(1.0f + __expf(-z));
}
__device__ __forceinline__ float tanh_f(float z) {
    return 2.0f * __builtin_amdgcn_rcpf(1.0f + __expf(-2.0f * z)) - 1.0f;
}

#define MFMA(A, B, C) __builtin_amdgcn_mfma_f32_16x16x32_bf16(A, B, C, 0, 0, 0)

// 8 waves, BT=4, two blocks per CU. Transposed MFMA, time-packed
// (B col = batch(0..3) + 8*dt). Per DSTEP td: rec(2td) w/ reg xzA;
// XGEMM(td+1) -> regs; barrier; rec(2td+1) w/ reg xz1s; stage x[td+2]; barrier.
// x and h stored bf16-hi only; weight lo-terms register-resident.
__global__ __launch_bounds__(512, 2)
void lstm_mfma_kernel(const float* __restrict__ x,  const float* __restrict__ Wx,
                      const float* __restrict__ Wh, const float* __restrict__ bg,
                      const float* __restrict__ W1, const float* __restrict__ b1,
                      const float* __restrict__ W2, const float* __restrict__ b2,
                      const float* __restrict__ Wo, const float* __restrict__ bo,
                      float* __restrict__ out)
{
    const int tid = threadIdx.x;     // 0..511
    const int w   = tid >> 6;        // wave id 0..7
    const int L   = tid & 63;
    const int c16 = L & 15;          // B col: batch(0..3) + 8*dt / D col
    const int kg  = L >> 4;          // k-group AND unit-offset of D rows
    const int bb  = blockIdx.x * BT;
    const int jj  = (w << 2) + kg;   // hidden unit owned by this lane

    // A row m=c16 -> weight column
    const int gcol = ((c16 & 3) << 5) + (w << 2) + (c16 >> 2);

    __shared__ __align__(16) unsigned short xh[4][16][XS];   // x hi-plane ring
    __shared__ __align__(16) unsigned short hh[2][16][HS];   // h hi-plane, parity
    __shared__ float Hd[3][BT][GS];

    // ---- register-resident weights (hi+lo) ----
    bf16x8 whh_, whl_, wx0h, wx0l, wx1h, wx1l;
#pragma unroll
    for (int i = 0; i < 8; ++i) {
        unsigned p = pack_split(Wx[(kg * 8 + i) * GQ + gcol]);
        wx0h[i] = (short)(unsigned short)(p >> 16);
        wx0l[i] = (short)(unsigned short)(p & 0xFFFFu);
        p = pack_split(Wx[(32 + kg * 8 + i) * GQ + gcol]);
        wx1h[i] = (short)(unsigned short)(p >> 16);
        wx1l[i] = (short)(unsigned short)(p & 0xFFFFu);
        p = pack_split(Wh[(kg * 8 + i) * GQ + gcol]);
        whh_[i] = (short)(unsigned short)(p >> 16);
        whl_[i] = (short)(unsigned short)(p & 0xFFFFu);
    }
    f32x4 biasC;
#pragma unroll
    for (int r = 0; r < 4; ++r) biasC[r] = bg[r * 32 + jj];
    const f32x4 zeroC = {0.f, 0.f, 0.f, 0.f};

    // ---- zero-init: h planes fully; x rows 4..7 and 12..15 (all slots) ----
    for (int i = tid; i < 2 * 16 * (HS / 2); i += 512)
        ((unsigned*)&hh[0][0][0])[i] = 0u;
    for (int i = tid; i < 4 * 8 * (XS / 2); i += 512) {
        int slot = i / (8 * (XS / 2));
        int rem  = i - slot * 8 * (XS / 2);
        int rr   = rem / (XS / 2);
        int row  = 4 + (rr & 3) + ((rr >> 2) << 3);   // 4..7, 12..15
        int col  = rem % (XS / 2);
        ((unsigned*)&xh[slot][row][0])[col] = 0u;
    }

    // staging map: one float per thread. sr = tid>>6: batch (sr&3), dt (sr>>2)
    const int sbat = (tid >> 6) & 3;
    const int sdt  = tid >> 8;       // 0/1
    const int srow = sbat + (sdt << 3);
    const int sfc  = tid & 63;       // feature
    const float* xsrc = x + (size_t)(bb + sbat) * S_ * F_ + sfc;
#pragma unroll
    for (int tt = 0; tt < 2; ++tt)
        xh[tt][srow][sfc] = bf16_rne(xsrc[(size_t)(2 * tt + sdt) * F_]);
    float xvA = xsrc[(size_t)(4 + sdt) * F_];   // slot 2
    float xvB = xsrc[(size_t)(6 + sdt) * F_];   // slot 3
    __syncthreads();

    // initial XGEMM (td=0) from slot 0 -> registers
    f32x4 xzA, xz1s;
    {
        bf16x8 bxh0 = *(const bf16x8*)&xh[0][c16][kg * 8];
        bf16x8 bxh1 = *(const bf16x8*)&xh[0][c16][32 + kg * 8];
        f32x4 b0 = MFMA(wx0h, bxh0, biasC);
        f32x4 b2 = MFMA(wx0l, bxh0, zeroC);
        b0 = MFMA(wx1h, bxh1, b0);
        b2 = MFMA(wx1l, bxh1, b2);
        f32x4 xs = b0 + b2;
        xzA = xs;
#pragma unroll
        for (int r = 0; r < 4; ++r) xz1s[r] = __shfl_xor(xs[r], 8);
    }

    float cc = 0.0f;

#define DSTEP(TD, XV) {                                                        \
    const int td = (TD);                                                       \
    int tl = td + 4; if (tl > 255) tl = 255;                                   \
    float xnext = xsrc[(size_t)(2 * tl + sdt) * F_];                           \
    /* phase 1: rec step 2td (h[2td-1] in plane 1) */                          \
    bf16x8 bhh = *(const bf16x8*)&hh[1][c16][kg * 8];                          \
    f32x4 a0 = MFMA(whh_, bhh, xzA);                                           \
    f32x4 a2 = MFMA(whl_, bhh, zeroC);                                         \
    f32x4 z = a0 + a2;                                                         \
    float iv = sigm(z[0]), fv = sigm(z[1]);                                    \
    float gv = tanh_f(z[2]), ov = sigm(z[3]);                                  \
    cc = fmaf(fv, cc, iv * gv);                                                \
    float hv = ov * tanh_f(cc);                                                \
    if (c16 < 4) hh[0][c16][jj] = bf16_rne(hv);                                \
    /* XGEMM(td+1) from slot (td+1)&3 -> next regs (independent of h) */       \
    f32x4 xzA_n, xz1s_n;                                                       \
    {                                                                          \
        const int s1 = (td + 1) & 3;                                           \
        bf16x8 bxh0 = *(const bf16x8*)&xh[s1][c16][kg * 8];                    \
        bf16x8 bxh1 = *(const bf16x8*)&xh[s1][c16][32 + kg * 8];               \
        f32x4 b0 = MFMA(wx0h, bxh0, biasC);                                    \
        f32x4 b2 = MFMA(wx0l, bxh0, zeroC);                                    \
        b0 = MFMA(wx1h, bxh1, b0);                                             \
        b2 = MFMA(wx1l, bxh1, b2);                                             \
        f32x4 xs = b0 + b2;                                                    \
        xzA_n = xs;                                                            \
        _Pragma("unroll")                                                      \
        for (int r = 0; r < 4; ++r) xz1s_n[r] = __shfl_xor(xs[r], 8);          \
    }                                                                          \
    __syncthreads();   /* A: h[2td] visible */                                 \
    /* phase 2: rec step 2td+1 (h[2td] in plane 0) */                          \
    bhh = *(const bf16x8*)&hh[0][c16][kg * 8];                                 \
    a0 = MFMA(whh_, bhh, xz1s);                                                \
    a2 = MFMA(whl_, bhh, zeroC);                                               \
    z = a0 + a2;                                                               \
    iv = sigm(z[0]); fv = sigm(z[1]);                                          \
    gv = tanh_f(z[2]); ov = sigm(z[3]);                                        \
    cc = fmaf(fv, cc, iv * gv);                                                \
    hv = ov * tanh_f(cc);                                                      \
    if (c16 < 4) {                                                             \
        hh[1][c16][jj] = bf16_rne(hv);                                         \
        if (td == 255) Hd[0][c16][jj] = hv;                                    \
    }                                                                          \
    /* stage slot td+2 from XV; reload XV for td+4 */                          \
    xh[(td + 2) & 3][srow][sfc] = bf16_rne(XV);                                \
    XV = xnext;                                                                \
    xzA = xzA_n; xz1s = xz1s_n;                                                \
    __syncthreads();   /* B: h[2td+1] + slot td+2 visible */                   \
}

    for (int qd = 0; qd < 128; ++qd) {
        DSTEP(2 * qd,     xvA)
        DSTEP(2 * qd + 1, xvB)
    }
#undef DSTEP

    __syncthreads();

    // ---- MLP head: 32 -> 32 -> 16 -> 3, leaky_relu(0.01) ----
    if (tid < BT * 32) {
        int rb = tid >> 5, n = tid & 31;
        float a = b1[n];
#pragma unroll
        for (int k = 0; k < 32; ++k) a = fmaf(Hd[0][rb][k], W1[k * 32 + n], a);
        a = (a > 0.0f) ? a : 0.01f * a;
        Hd[1][rb][n] = a;
    }
    __syncthreads();
    if (tid < BT * 16) {
        int rb = tid >> 4, n = tid & 15;
        float a = b2[n];
#pragma unroll
        for (int k = 0; k < 32; ++k) a = fmaf(Hd[1][rb][k], W2[k * 16 + n], a);
        a = (a > 0.0f) ? a : 0.01f * a;
        Hd[2][rb][n] = a;
    }
    __syncthreads();
    if (tid < BT * 3) {
        int rb = tid / 3, n = tid - rb * 3;
        float a = bo[n];
#pragma unroll
        for (int k = 0; k < 16; ++k) a = fmaf(Hd[2][rb][k], Wo[k * 3 + n], a);
        out[(size_t)(bb + rb) * 3 + n] = a;
    }
}

extern "C" void kernel_launch(void* const* d_in, const int* in_sizes, int n_in,
                              void* d_out, int out_size, void* d_ws, size_t ws_size,
                              hipStream_t stream) {
    const float* x  = (const float*)d_in[0];
    const float* Wx = (const float*)d_in[1];
    const float* Wh = (const float*)d_in[2];
    const float* bg = (const float*)d_in[3];
    const float* W1 = (const float*)d_in[4];
    const float* b1 = (const float*)d_in[5];
    const float* W2 = (const float*)d_in[6];
    const float* b2 = (const float*)d_in[7];
    const float* Wo = (const float*)d_in[8];
    const float* bo = (const float*)d_in[9];
    float* out = (float*)d_out;

    hipLaunchKernelGGL(lstm_mfma_kernel, dim3(NB), dim3(512), 0, stream,
                       x, Wx, Wh, bg, W1, b1, W2, b2, Wo, bo, out);
}

// Round 15
// 177.573 us; speedup vs baseline: 1.4306x; 1.4306x over previous
//
#include <hip/hip_runtime.h>

#define S_  512
#define F_  64
#define H_  32
#define GQ  128   // 4*H
#define BT  8     // real batch rows per block
#define NB  256   // 2048/BT -> one block per CU

#define XS  72    // x plane row stride (ushorts)
#define HS  40    // h plane row stride (ushorts)
#define GS  33    // head buffer row stride (floats)

typedef __attribute__((ext_vector_type(8))) short bf16x8;
typedef __attribute__((ext_vector_type(4))) float f32x4;

// f32 -> (bf16_hi << 16) | bf16_lo, both RNE
__device__ __forceinline__ unsigned pack_split(float f) {
    unsigned u  = __builtin_bit_cast(unsigned, f);
    unsigned hi = (u + 0x7FFFu + ((u >> 16) & 1u)) & 0xFFFF0000u;
    float    fl = f - __builtin_bit_cast(float, hi);
    unsigned ul = __builtin_bit_cast(unsigned, fl);
    unsigned lo = (ul + 0x7FFFu + ((ul >> 16) & 1u)) >> 16;
    return hi | lo;
}

// f32 -> bf16 (RNE)
__device__ __forceinline__ unsigned short bf16_rne(float f) {
    unsigned u = __builtin_bit_cast(unsigned, f);
    return (unsigned short)((u + 0x7FFFu + ((u >> 16) & 1u)) >> 16);
}

__device__ __forceinline__ float sigm(float z) {
    return __builtin_amdgcn_rcpf(1.0f + __expf(-z));
}
__device__ __forceinline__ float tanh_f(float z) {
    return 2.0f * __builtin_amdgcn_rcpf(1.0f + __expf(-2.0f * z)) - 1.0f;
}

#define MFMA(A, B, C) __builtin_amdgcn_mfma_f32_16x16x32_bf16(A, B, C, 0, 0, 0)

// 8 waves, BT=8, one block/CU. Transposed MFMA, time-packed (col = batch + 8*dt).
// DSTEP layout (R15): ALL long-latency ops issued at top (global xnext, x-slot
// reads for XGEMM(td+1), h plane-1 read for phase1) so barrier drains are cheap;
// XGEMM overlaps the load latency; phase2 chain is the only exposed serial part.
__global__ __launch_bounds__(512, 1)
void lstm_mfma_kernel(const float* __restrict__ x,  const float* __restrict__ Wx,
                      const float* __restrict__ Wh, const float* __restrict__ bg,
                      const float* __restrict__ W1, const float* __restrict__ b1,
                      const float* __restrict__ W2, const float* __restrict__ b2,
                      const float* __restrict__ Wo, const float* __restrict__ bo,
                      float* __restrict__ out)
{
    const int tid = threadIdx.x;     // 0..511
    const int w   = tid >> 6;        // wave id 0..7
    const int L   = tid & 63;
    const int c16 = L & 15;          // B col: batch(0..7) + 8*dt / D col
    const int kg  = L >> 4;          // k-group AND unit-offset of D rows
    const int bb  = blockIdx.x * BT;
    const int jj  = (w << 2) + kg;   // hidden unit owned by this lane

    // A row m=c16 -> weight column
    const int gcol = ((c16 & 3) << 5) + (w << 2) + (c16 >> 2);

    __shared__ __align__(16) unsigned short xh[4][16][XS];   // x hi-plane ring
    __shared__ __align__(16) unsigned short hh[2][16][HS];   // h hi-plane, parity
    __shared__ float Hd[3][BT][GS];

    // ---- register-resident weights (hi+lo) ----
    bf16x8 whh_, whl_, wx0h, wx0l, wx1h, wx1l;
#pragma unroll
    for (int i = 0; i < 8; ++i) {
        unsigned p = pack_split(Wx[(kg * 8 + i) * GQ + gcol]);
        wx0h[i] = (short)(unsigned short)(p >> 16);
        wx0l[i] = (short)(unsigned short)(p & 0xFFFFu);
        p = pack_split(Wx[(32 + kg * 8 + i) * GQ + gcol]);
        wx1h[i] = (short)(unsigned short)(p >> 16);
        wx1l[i] = (short)(unsigned short)(p & 0xFFFFu);
        p = pack_split(Wh[(kg * 8 + i) * GQ + gcol]);
        whh_[i] = (short)(unsigned short)(p >> 16);
        whl_[i] = (short)(unsigned short)(p & 0xFFFFu);
    }
    f32x4 biasC;
#pragma unroll
    for (int r = 0; r < 4; ++r) biasC[r] = bg[r * 32 + jj];
    const f32x4 zeroC = {0.f, 0.f, 0.f, 0.f};

    // ---- zero h planes (rows 8..15 stay zero forever) ----
    for (int i = tid; i < 2 * 16 * (HS / 2); i += 512)
        ((unsigned*)&hh[0][0][0])[i] = 0u;

    // staging map: row = batch(0..7) + 8*dt, feature pair; 1 u32 write per lane
    const int srow = tid >> 5;       // 0..15
    const int sfp  = tid & 31;       // feature pair
    const int sdt  = srow >> 3;      // dt 0/1
    const float* xsrc = x + (size_t)(bb + (srow & 7)) * S_ * F_ + 2 * sfp;
    {
#pragma unroll
        for (int tt = 0; tt < 2; ++tt) {
            float2 v = *(const float2*)(xsrc + (size_t)(2 * tt + sdt) * F_);
            *(unsigned*)&xh[tt][srow][2 * sfp] =
                (unsigned)bf16_rne(v.x) | ((unsigned)bf16_rne(v.y) << 16);
        }
    }
    float2 xvA = *(const float2*)(xsrc + (size_t)(4 + sdt) * F_);   // slot 2
    float2 xvB = *(const float2*)(xsrc + (size_t)(6 + sdt) * F_);   // slot 3
    __syncthreads();

    // initial XGEMM (td=0) from slot 0 -> registers
    f32x4 xzA, xz1s;
    {
        bf16x8 bxh0 = *(const bf16x8*)&xh[0][c16][kg * 8];
        bf16x8 bxh1 = *(const bf16x8*)&xh[0][c16][32 + kg * 8];
        f32x4 b0 = MFMA(wx0h, bxh0, biasC);
        f32x4 b2 = MFMA(wx0l, bxh0, zeroC);
        b0 = MFMA(wx1h, bxh1, b0);
        b2 = MFMA(wx1l, bxh1, b2);
        f32x4 xs = b0 + b2;
        xzA = xs;
#pragma unroll
        for (int r = 0; r < 4; ++r) xz1s[r] = __shfl_xor(xs[r], 8);
    }

    float cc = 0.0f;

#define DSTEP(TD, XV) {                                                        \
    const int td = (TD);                                                       \
    /* ---- top: issue ALL long-latency loads (post barrier B of td-1) ---- */ \
    int tl = td + 4; if (tl > 255) tl = 255;                                   \
    float2 xnext = *(const float2*)(xsrc + (size_t)(2 * tl + sdt) * F_);       \
    const int s1 = (td + 1) & 3;                                               \
    bf16x8 bxh0 = *(const bf16x8*)&xh[s1][c16][kg * 8];                        \
    bf16x8 bxh1 = *(const bf16x8*)&xh[s1][c16][32 + kg * 8];                   \
    bf16x8 bhh1 = *(const bf16x8*)&hh[1][c16][kg * 8];   /* h[2td-1] */        \
    /* ---- XGEMM(td+1) overlaps the loads' latency ---- */                    \
    f32x4 xzA_n, xz1s_n;                                                       \
    {                                                                          \
        f32x4 b0 = MFMA(wx0h, bxh0, biasC);                                    \
        f32x4 b2 = MFMA(wx0l, bxh0, zeroC);                                    \
        b0 = MFMA(wx1h, bxh1, b0);                                             \
        b2 = MFMA(wx1l, bxh1, b2);                                             \
        f32x4 xsv = b0 + b2;                                                   \
        xzA_n = xsv;                                                           \
        _Pragma("unroll")                                                      \
        for (int r = 0; r < 4; ++r) xz1s_n[r] = __shfl_xor(xsv[r], 8);         \
    }                                                                          \
    /* ---- phase 1: rec step 2td ---- */                                      \
    {                                                                          \
        f32x4 a0 = MFMA(whh_, bhh1, xzA);                                      \
        f32x4 a2 = MFMA(whl_, bhh1, zeroC);                                    \
        f32x4 z = a0 + a2;                                                     \
        float iv = sigm(z[0]), fv = sigm(z[1]);                                \
        float gv = tanh_f(z[2]), ov = sigm(z[3]);                              \
        cc = fmaf(fv, cc, iv * gv);                                            \
        float hv = ov * tanh_f(cc);                                            \
        if (c16 < 8) hh[0][c16][jj] = bf16_rne(hv);                            \
    }                                                                          \
    __syncthreads();   /* A: h[2td] visible; queue nearly drained already */   \
    /* ---- phase 2: rec step 2td+1 ---- */                                    \
    {                                                                          \
        bf16x8 bhh0 = *(const bf16x8*)&hh[0][c16][kg * 8];                     \
        f32x4 a0 = MFMA(whh_, bhh0, xz1s);                                     \
        f32x4 a2 = MFMA(whl_, bhh0, zeroC);                                    \
        f32x4 z = a0 + a2;                                                     \
        float iv = sigm(z[0]), fv = sigm(z[1]);                                \
        float gv = tanh_f(z[2]), ov = sigm(z[3]);                              \
        cc = fmaf(fv, cc, iv * gv);                                            \
        float hv = ov * tanh_f(cc);                                            \
        if (c16 < 8) {                                                         \
            hh[1][c16][jj] = bf16_rne(hv);                                     \
            if (td == 255) Hd[0][c16][jj] = hv;                                \
        }                                                                      \
    }                                                                          \
    /* stage slot td+2 from XV; rotate prefetch regs */                        \
    *(unsigned*)&xh[(td + 2) & 3][srow][2 * sfp] =                             \
        (unsigned)bf16_rne(XV.x) | ((unsigned)bf16_rne(XV.y) << 16);           \
    XV = xnext;                                                                \
    xzA = xzA_n; xz1s = xz1s_n;                                                \
    __syncthreads();   /* B: h[2td+1] + slot td+2 visible */                   \
}

    for (int qd = 0; qd < 128; ++qd) {
        DSTEP(2 * qd,     xvA)
        DSTEP(2 * qd + 1, xvB)
    }
#undef DSTEP

    __syncthreads();

    // ---- MLP head: 32 -> 32 -> 16 -> 3, leaky_relu(0.01) ----
    if (tid < 256) {
        int rb = tid >> 5, n = tid & 31;
        float a = b1[n];
#pragma unroll
        for (int k = 0; k < 32; ++k) a = fmaf(Hd[0][rb][k], W1[k * 32 + n], a);
        a = (a > 0.0f) ? a : 0.01f * a;
        Hd[1][rb][n] = a;
    }
    __syncthreads();
    if (tid < 128) {
        int rb = tid >> 4, n = tid & 15;
        float a = b2[n];
#pragma unroll
        for (int k = 0; k < 32; ++k) a = fmaf(Hd[1][rb][k], W2[k * 16 + n], a);
        a = (a > 0.0f) ? a : 0.01f * a;
        Hd[2][rb][n] = a;
    }
    __syncthreads();
    if (tid < 24) {
        int rb = tid / 3, n = tid - rb * 3;
        float a = bo[n];
#pragma unroll
        for (int k = 0; k < 16; ++k) a = fmaf(Hd[2][rb][k], Wo[k * 3 + n], a);
        out[(size_t)(bb + rb) * 3 + n] = a;
    }
}

extern "C" void kernel_launch(void* const* d_in, const int* in_sizes, int n_in,
                              void* d_out, int out_size, void* d_ws, size_t ws_size,
                              hipStream_t stream) {
    const float* x  = (const float*)d_in[0];
    const float* Wx = (const float*)d_in[1];
    const float* Wh = (const float*)d_in[2];
    const float* bg = (const float*)d_in[3];
    const float* W1 = (const float*)d_in[4];
    const float* b1 = (const float*)d_in[5];
    const float* W2 = (const float*)d_in[6];
    const float* b2 = (const float*)d_in[7];
    const float* Wo = (const float*)d_in[8];
    const float* bo = (const float*)d_in[9];
    float* out = (float*)d_out;

    hipLaunchKernelGGL(lstm_mfma_kernel, dim3(NB), dim3(512), 0, stream,
                       x, Wx, Wh, bg, W1, b1, W2, b2, Wo, bo, out);
}